// Round 1
// baseline (18049.756 us; speedup 1.0000x reference)
//
#include <hip/hip_runtime.h>

#define DEVINL __device__ __forceinline__

DEVINL void fma4(float4& a, const float4 w, const float x) {
    a.x += w.x * x; a.y += w.y * x; a.z += w.z * x; a.w += w.w * x;
}

// ---------------------------------------------------------------------------
// Edge kernel: for each edge e, m = relu(cat(h[src[e]], efeat[e]) @ W + b),
// then atomicAdd into agg[dst[e]].
// h rows have stride FINP (>= FIN, multiple of 4), pad entries are zero.
// W is [(FIN+64) x FOUT] row-major. agg is [N x FOUT] packed, pre-zeroed.
// ---------------------------------------------------------------------------
template<int FIN, int FINP, int FOUT, int FOUTP, int EPT>
__global__ __launch_bounds__(256) void edge_kernel(
    const float* __restrict__ h,
    const float* __restrict__ efeats,
    const int* __restrict__ src,
    const int* __restrict__ dstv,
    const float* __restrict__ W,
    const float* __restrict__ b,
    float* __restrict__ agg,
    int nEdges)
{
    constexpr int K  = FINP + 64;   // padded input length
    constexpr int F4 = FOUTP / 4;

    __shared__ float4 Wl[K * F4];
    __shared__ float4 bl[F4];

    const int tid = threadIdx.x;

    // Stage padded W into LDS: rows [0,FIN) = h-part of W, [FIN,FINP) = 0,
    // [FINP,FINP+64) = e-part of W. Cols >= FOUT are 0.
    for (int idx = tid; idx < K * FOUTP; idx += 256) {
        int k = idx / FOUTP;
        int j = idx - k * FOUTP;
        float v = 0.f;
        if (j < FOUT) {
            if (k < FIN)        v = W[k * FOUT + j];
            else if (k >= FINP) v = W[(FIN + (k - FINP)) * FOUT + j];
        }
        reinterpret_cast<float*>(Wl)[idx] = v;
    }
    for (int idx = tid; idx < FOUTP; idx += 256)
        reinterpret_cast<float*>(bl)[idx] = (idx < FOUT) ? b[idx] : 0.f;
    __syncthreads();

    const long long e0 = (long long)blockIdx.x * (256 * EPT) + tid;

    float4 acc[EPT][F4];
    int sIdx[EPT], dIdx[EPT];
    bool valid[EPT];
    const float4* erow[EPT];

    #pragma unroll
    for (int i = 0; i < EPT; i++) {
        long long e = e0 + (long long)i * 256;
        valid[i] = (e < nEdges);
        long long esafe = valid[i] ? e : 0;
        sIdx[i] = src[esafe];
        dIdx[i] = dstv[esafe];
        erow[i] = reinterpret_cast<const float4*>(efeats + esafe * 64);
        #pragma unroll
        for (int j4 = 0; j4 < F4; j4++) acc[i][j4] = bl[j4];
    }

    // h[src] part
    for (int k4 = 0; k4 < FINP / 4; k4++) {
        float4 xv[EPT];
        #pragma unroll
        for (int i = 0; i < EPT; i++)
            xv[i] = *reinterpret_cast<const float4*>(h + (long long)sIdx[i] * FINP + k4 * 4);
        #pragma unroll
        for (int c = 0; c < 4; c++) {
            const float4* wrow = &Wl[(k4 * 4 + c) * F4];
            #pragma unroll
            for (int j4 = 0; j4 < F4; j4++) {
                float4 w = wrow[j4];
                #pragma unroll
                for (int i = 0; i < EPT; i++) {
                    float xc = (c == 0) ? xv[i].x : (c == 1) ? xv[i].y : (c == 2) ? xv[i].z : xv[i].w;
                    fma4(acc[i][j4], w, xc);
                }
            }
        }
    }

    // efeat part
    for (int k4 = 0; k4 < 16; k4++) {
        float4 xv[EPT];
        #pragma unroll
        for (int i = 0; i < EPT; i++) xv[i] = erow[i][k4];
        #pragma unroll
        for (int c = 0; c < 4; c++) {
            const float4* wrow = &Wl[(FINP + k4 * 4 + c) * F4];
            #pragma unroll
            for (int j4 = 0; j4 < F4; j4++) {
                float4 w = wrow[j4];
                #pragma unroll
                for (int i = 0; i < EPT; i++) {
                    float xc = (c == 0) ? xv[i].x : (c == 1) ? xv[i].y : (c == 2) ? xv[i].z : xv[i].w;
                    fma4(acc[i][j4], w, xc);
                }
            }
        }
    }

    // relu + scatter-add
    #pragma unroll
    for (int i = 0; i < EPT; i++) {
        if (!valid[i]) continue;
        float* arow = agg + (long long)dIdx[i] * FOUT;
        #pragma unroll
        for (int j4 = 0; j4 < F4; j4++) {
            float4 a = acc[i][j4];
            if (4 * j4 + 0 < FOUT) atomicAdd(arow + 4 * j4 + 0, fmaxf(a.x, 0.f));
            if (4 * j4 + 1 < FOUT) atomicAdd(arow + 4 * j4 + 1, fmaxf(a.y, 0.f));
            if (4 * j4 + 2 < FOUT) atomicAdd(arow + 4 * j4 + 2, fmaxf(a.z, 0.f));
            if (4 * j4 + 3 < FOUT) atomicAdd(arow + 4 * j4 + 3, fmaxf(a.w, 0.f));
        }
    }
}

// ---------------------------------------------------------------------------
// Node kernel: out = relu(cat(h, agg) @ W + b), one thread per node.
// h rows stride FHP (pad zero), agg rows packed stride FAGG,
// out rows stride FOUTP with zero pads (acc pads stay 0).
// ---------------------------------------------------------------------------
template<int FH, int FHP, int FAGG, int FOUT, int FOUTP>
__global__ __launch_bounds__(256) void node_kernel(
    const float* __restrict__ h,
    const float* __restrict__ agg,
    const float* __restrict__ W,
    const float* __restrict__ b,
    float* __restrict__ out,
    int nNodes)
{
    constexpr int K  = FH + FAGG;
    constexpr int F4 = FOUTP / 4;

    __shared__ float4 Wl[K * F4];
    __shared__ float4 bl[F4];

    const int tid = threadIdx.x;
    for (int idx = tid; idx < K * FOUTP; idx += 256) {
        int k = idx / FOUTP;
        int j = idx - k * FOUTP;
        reinterpret_cast<float*>(Wl)[idx] = (j < FOUT) ? W[k * FOUT + j] : 0.f;
    }
    for (int idx = tid; idx < FOUTP; idx += 256)
        reinterpret_cast<float*>(bl)[idx] = (idx < FOUT) ? b[idx] : 0.f;
    __syncthreads();

    const int n = blockIdx.x * 256 + tid;
    if (n >= nNodes) return;

    float4 acc[F4];
    #pragma unroll
    for (int j4 = 0; j4 < F4; j4++) acc[j4] = bl[j4];

    const float* hrow = h + (long long)n * FHP;
    for (int k = 0; k < FH; k++) {
        float xk = hrow[k];
        const float4* wrow = &Wl[k * F4];
        #pragma unroll
        for (int j4 = 0; j4 < F4; j4++) fma4(acc[j4], wrow[j4], xk);
    }
    const float* arow = agg + (long long)n * FAGG;
    for (int k = 0; k < FAGG; k++) {
        float xk = arow[k];
        const float4* wrow = &Wl[(FH + k) * F4];
        #pragma unroll
        for (int j4 = 0; j4 < F4; j4++) fma4(acc[j4], wrow[j4], xk);
    }

    float4* orow = reinterpret_cast<float4*>(out + (long long)n * FOUTP);
    #pragma unroll
    for (int j4 = 0; j4 < F4; j4++) {
        float4 a = acc[j4];
        a.x = fmaxf(a.x, 0.f); a.y = fmaxf(a.y, 0.f);
        a.z = fmaxf(a.z, 0.f); a.w = fmaxf(a.w, 0.f);
        orow[j4] = a;
    }
}

extern "C" void kernel_launch(void* const* d_in, const int* in_sizes, int n_in,
                              void* d_out, int out_size, void* d_ws, size_t ws_size,
                              hipStream_t stream)
{
    const float* nfeats = (const float*)d_in[0];
    const float* efeats = (const float*)d_in[1];
    const int*   src    = (const int*)d_in[2];
    const int*   dst    = (const int*)d_in[3];
    const float* Wm1 = (const float*)d_in[4],  *bm1 = (const float*)d_in[5];
    const float* Wa1 = (const float*)d_in[6],  *ba1 = (const float*)d_in[7];
    const float* Wm2 = (const float*)d_in[8],  *bm2 = (const float*)d_in[9];
    const float* Wa2 = (const float*)d_in[10], *ba2 = (const float*)d_in[11];
    const float* Wm3 = (const float*)d_in[12], *bm3 = (const float*)d_in[13];
    const float* Wa3 = (const float*)d_in[14], *ba3 = (const float*)d_in[15];
    float* out = (float*)d_out;

    constexpr int N = 100000;
    constexpr int E = 3200000;

    float* ws  = (float*)d_ws;
    float* h1  = ws;                          // N x 52 (50 + zero pad)
    float* h2  = h1 + (size_t)N * 52;         // N x 28 (25 + zero pad)
    float* agg = h2 + (size_t)N * 28;         // N x 52 scratch aggregation

    const int EB = (E + 511) / 512;           // EPT=2, 256 threads
    const int NB = (N + 255) / 256;

    // ---- layer 1 ----
    hipMemsetAsync(agg, 0, (size_t)N * 52 * sizeof(float), stream);
    edge_kernel<64, 64, 50, 52, 2><<<EB, 256, 0, stream>>>(nfeats, efeats, src, dst, Wm1, bm1, agg, E);
    node_kernel<64, 64, 50, 50, 52><<<NB, 256, 0, stream>>>(nfeats, agg, Wa1, ba1, h1, N);

    // ---- layer 2 ----
    hipMemsetAsync(agg, 0, (size_t)N * 52 * sizeof(float), stream);
    edge_kernel<50, 52, 25, 28, 2><<<EB, 256, 0, stream>>>(h1, efeats, src, dst, Wm2, bm2, agg, E);
    node_kernel<50, 52, 25, 25, 28><<<NB, 256, 0, stream>>>(h1, agg, Wa2, ba2, h2, N);

    // ---- layer 3 ----
    hipMemsetAsync(agg, 0, (size_t)N * 52 * sizeof(float), stream);
    edge_kernel<25, 28, 32, 32, 2><<<EB, 256, 0, stream>>>(h2, efeats, src, dst, Wm3, bm3, agg, E);
    node_kernel<25, 28, 32, 32, 32><<<NB, 256, 0, stream>>>(h2, agg, Wa3, ba3, out, N);
}

// Round 2
// 3129.678 us; speedup vs baseline: 5.7673x; 5.7673x over previous
//
#include <hip/hip_runtime.h>

#define DEVINL __device__ __forceinline__

DEVINL void fma4(float4& a, const float4 w, const float x) {
    a.x += w.x * x; a.y += w.y * x; a.z += w.z * x; a.w += w.w * x;
}

// ---------------------------------------------------------------------------
// Edge kernel: thread-per-edge GEMV m = relu(cat(h[src],e)@W+b), then a
// coalesced scatter phase: messages round-trip through LDS so that FOUT
// consecutive lanes issue the FOUT atomics of ONE edge (2-3 cache lines)
// instead of per-lane scattered atomics (64 lines per instruction).
// Grid is sized exactly: nEdges % 256 == 0.
// MS = LDS message row stride in dwords (odd => conflict-free writes).
// ---------------------------------------------------------------------------
template<int FIN, int FINP, int FOUT, int FOUTP, int MS>
__global__ __launch_bounds__(256) void edge_kernel(
    const float* __restrict__ h,
    const float* __restrict__ efeats,
    const int* __restrict__ src,
    const int* __restrict__ dstv,
    const float* __restrict__ W,
    const float* __restrict__ b,
    float* __restrict__ agg)
{
    constexpr int K   = FINP + 64;      // padded input length
    constexpr int F4  = FOUTP / 4;
    constexpr int WSZ = K * F4;                 // W tile, in float4
    constexpr int MSZ = (128 * MS + 3) / 4;     // half-batch msg buf, in float4
    constexpr int SM4 = (WSZ > MSZ) ? WSZ : MSZ;

    __shared__ float4 smem[SM4];        // union: W tile (compute) / msg (flush)
    __shared__ float  bl[FOUTP];

    float4* Wl  = smem;
    float*  msg = reinterpret_cast<float*>(smem);

    const int tid = threadIdx.x;

    // Stage padded W into LDS: rows [0,FIN) = h-part, [FIN,FINP) = 0,
    // [FINP,FINP+64) = e-part. Cols >= FOUT are 0.
    for (int idx = tid; idx < K * FOUTP; idx += 256) {
        int k = idx / FOUTP;
        int j = idx - k * FOUTP;
        float v = 0.f;
        if (j < FOUT) {
            if (k < FIN)        v = W[k * FOUT + j];
            else if (k >= FINP) v = W[(FIN + (k - FINP)) * FOUT + j];
        }
        reinterpret_cast<float*>(Wl)[idx] = v;
    }
    if (tid < FOUTP) bl[tid] = (tid < FOUT) ? b[tid] : 0.f;
    __syncthreads();

    const int e = blockIdx.x * 256 + tid;
    const int sIdx = src[e];
    const float4* erow = reinterpret_cast<const float4*>(efeats + (long long)e * 64);
    const float4* hrow = reinterpret_cast<const float4*>(h + (long long)sIdx * FINP);

    float4 acc[F4];
    #pragma unroll
    for (int j4 = 0; j4 < F4; j4++) acc[j4] = reinterpret_cast<float4*>(bl)[j4];

    // h[src] part
    #pragma unroll
    for (int k4 = 0; k4 < FINP / 4; k4++) {
        float4 xv = hrow[k4];
        #pragma unroll
        for (int c = 0; c < 4; c++) {
            float xc = (c == 0) ? xv.x : (c == 1) ? xv.y : (c == 2) ? xv.z : xv.w;
            const float4* wrow = &Wl[(k4 * 4 + c) * F4];
            #pragma unroll
            for (int j4 = 0; j4 < F4; j4++) fma4(acc[j4], wrow[j4], xc);
        }
    }
    // efeat part
    #pragma unroll
    for (int k4 = 0; k4 < 16; k4++) {
        float4 xv = erow[k4];
        #pragma unroll
        for (int c = 0; c < 4; c++) {
            float xc = (c == 0) ? xv.x : (c == 1) ? xv.y : (c == 2) ? xv.z : xv.w;
            const float4* wrow = &Wl[(FINP + k4 * 4 + c) * F4];
            #pragma unroll
            for (int j4 = 0; j4 < F4; j4++) fma4(acc[j4], wrow[j4], xc);
        }
    }

    __syncthreads();   // all W reads done; smem may be reused for messages

    // Coalesced scatter: two half-batches of 128 edges through LDS.
    constexpr int JL   = (FOUT > 32) ? 64 : 32;   // lanes per edge in flush
    constexpr int ITER = 128 * JL / 256;

    #pragma unroll
    for (int half = 0; half < 2; ++half) {
        if ((tid >> 7) == half) {
            int le = tid & 127;
            #pragma unroll
            for (int j4 = 0; j4 < F4; j4++) {
                float4 a = acc[j4];
                if (4 * j4 + 0 < FOUT) msg[le * MS + 4 * j4 + 0] = fmaxf(a.x, 0.f);
                if (4 * j4 + 1 < FOUT) msg[le * MS + 4 * j4 + 1] = fmaxf(a.y, 0.f);
                if (4 * j4 + 2 < FOUT) msg[le * MS + 4 * j4 + 2] = fmaxf(a.z, 0.f);
                if (4 * j4 + 3 < FOUT) msg[le * MS + 4 * j4 + 3] = fmaxf(a.w, 0.f);
            }
        }
        __syncthreads();
        for (int it = 0; it < ITER; ++it) {
            int p  = it * 256 + tid;
            int le = p / JL;
            int j  = p & (JL - 1);
            if (j < FOUT) {
                int eg = blockIdx.x * 256 + half * 128 + le;
                int d  = dstv[eg];
                atomicAdd(agg + (long long)d * FOUT + j, msg[le * MS + j]);
            }
        }
        __syncthreads();
    }
}

// ---------------------------------------------------------------------------
// Node kernel: out = relu(cat(h, agg) @ W + b), one thread per node.
// ---------------------------------------------------------------------------
template<int FH, int FHP, int FAGG, int FOUT, int FOUTP>
__global__ __launch_bounds__(256) void node_kernel(
    const float* __restrict__ h,
    const float* __restrict__ agg,
    const float* __restrict__ W,
    const float* __restrict__ b,
    float* __restrict__ out,
    int nNodes)
{
    constexpr int K  = FH + FAGG;
    constexpr int F4 = FOUTP / 4;

    __shared__ float4 Wl[K * F4];
    __shared__ float4 bl[F4];

    const int tid = threadIdx.x;
    for (int idx = tid; idx < K * FOUTP; idx += 256) {
        int k = idx / FOUTP;
        int j = idx - k * FOUTP;
        reinterpret_cast<float*>(Wl)[idx] = (j < FOUT) ? W[k * FOUT + j] : 0.f;
    }
    for (int idx = tid; idx < FOUTP; idx += 256)
        reinterpret_cast<float*>(bl)[idx] = (idx < FOUT) ? b[idx] : 0.f;
    __syncthreads();

    const int n = blockIdx.x * 256 + tid;
    if (n >= nNodes) return;

    float4 acc[F4];
    #pragma unroll
    for (int j4 = 0; j4 < F4; j4++) acc[j4] = bl[j4];

    const float* hrow = h + (long long)n * FHP;
    for (int k = 0; k < FH; k++) {
        float xk = hrow[k];
        const float4* wrow = &Wl[k * F4];
        #pragma unroll
        for (int j4 = 0; j4 < F4; j4++) fma4(acc[j4], wrow[j4], xk);
    }
    const float* arow = agg + (long long)n * FAGG;
    for (int k = 0; k < FAGG; k++) {
        float xk = arow[k];
        const float4* wrow = &Wl[(FH + k) * F4];
        #pragma unroll
        for (int j4 = 0; j4 < F4; j4++) fma4(acc[j4], wrow[j4], xk);
    }

    float4* orow = reinterpret_cast<float4*>(out + (long long)n * FOUTP);
    #pragma unroll
    for (int j4 = 0; j4 < F4; j4++) {
        float4 a = acc[j4];
        a.x = fmaxf(a.x, 0.f); a.y = fmaxf(a.y, 0.f);
        a.z = fmaxf(a.z, 0.f); a.w = fmaxf(a.w, 0.f);
        orow[j4] = a;
    }
}

extern "C" void kernel_launch(void* const* d_in, const int* in_sizes, int n_in,
                              void* d_out, int out_size, void* d_ws, size_t ws_size,
                              hipStream_t stream)
{
    const float* nfeats = (const float*)d_in[0];
    const float* efeats = (const float*)d_in[1];
    const int*   src    = (const int*)d_in[2];
    const int*   dst    = (const int*)d_in[3];
    const float* Wm1 = (const float*)d_in[4],  *bm1 = (const float*)d_in[5];
    const float* Wa1 = (const float*)d_in[6],  *ba1 = (const float*)d_in[7];
    const float* Wm2 = (const float*)d_in[8],  *bm2 = (const float*)d_in[9];
    const float* Wa2 = (const float*)d_in[10], *ba2 = (const float*)d_in[11];
    const float* Wm3 = (const float*)d_in[12], *bm3 = (const float*)d_in[13];
    const float* Wa3 = (const float*)d_in[14], *ba3 = (const float*)d_in[15];
    float* out = (float*)d_out;

    constexpr int N = 100000;
    constexpr int E = 3200000;   // divisible by 256

    float* ws  = (float*)d_ws;
    float* h1  = ws;                          // N x 52 (50 + zero pad)
    float* h2  = h1 + (size_t)N * 52;         // N x 28 (25 + zero pad)
    float* agg = h2 + (size_t)N * 28;         // N x 52 scratch aggregation

    const int EB = E / 256;
    const int NB = (N + 255) / 256;

    // ---- layer 1 ----  (edge: FIN=64 FOUT=50, MS=51; node: 64+50 -> 50)
    hipMemsetAsync(agg, 0, (size_t)N * 52 * sizeof(float), stream);
    edge_kernel<64, 64, 50, 52, 51><<<EB, 256, 0, stream>>>(nfeats, efeats, src, dst, Wm1, bm1, agg);
    node_kernel<64, 64, 50, 50, 52><<<NB, 256, 0, stream>>>(nfeats, agg, Wa1, ba1, h1, N);

    // ---- layer 2 ----  (edge: FIN=50 FOUT=25, MS=25; node: 50+25 -> 25)
    hipMemsetAsync(agg, 0, (size_t)N * 52 * sizeof(float), stream);
    edge_kernel<50, 52, 25, 28, 25><<<EB, 256, 0, stream>>>(h1, efeats, src, dst, Wm2, bm2, agg);
    node_kernel<50, 52, 25, 25, 28><<<NB, 256, 0, stream>>>(h1, agg, Wa2, ba2, h2, N);

    // ---- layer 3 ----  (edge: FIN=25 FOUT=32, MS=33; node: 25+32 -> 32)
    hipMemsetAsync(agg, 0, (size_t)N * 52 * sizeof(float), stream);
    edge_kernel<25, 28, 32, 32, 33><<<EB, 256, 0, stream>>>(h2, efeats, src, dst, Wm3, bm3, agg);
    node_kernel<25, 28, 32, 32, 32><<<NB, 256, 0, stream>>>(h2, agg, Wa3, ba3, out, N);
}